// Round 1
// baseline (176.167 us; speedup 1.0000x reference)
//
#include <hip/hip_runtime.h>

#define B_    16
#define CIN_  128
#define COUT_ 256
#define H_    56
#define W_    56
#define YP    58
#define XP    64

typedef __bf16 bf16;
typedef bf16  bf16x8 __attribute__((ext_vector_type(8)));
typedef float f32x4  __attribute__((ext_vector_type(4)));
typedef float f4     __attribute__((ext_vector_type(4)));

// ---------------------------------------------------------------------------
// async global->LDS, 16B per lane. LDS dest must be wave-uniform base; HW
// writes lane l at base + l*16.
__device__ __forceinline__ void gload16(const bf16* g, bf16* l) {
    __builtin_amdgcn_global_load_lds(
        (const __attribute__((address_space(1))) unsigned int*)g,
        (__attribute__((address_space(3))) unsigned int*)l,
        16, 0, 0);
}

// ---------------------------------------------------------------------------
// Kernel A: quantize x (NCHW fp32) -> xqT[b][y][x][cin] bf16, spatially padded
// (y=0,57 and x=0,57..63 are zeros). One block per (b, y) row.
__global__ __launch_bounds__(256) void k_quant(
    const float* __restrict__ x,
    const float* __restrict__ p_act_s, const float* __restrict__ p_act_q,
    const float* __restrict__ p_azp,  const float* __restrict__ p_guard_a,
    bf16* __restrict__ xqT)
{
    int blk = blockIdx.x;            // b*58 + y
    int b = blk / YP, y = blk - b * YP;
    int t = threadIdx.x;
    __shared__ bf16 shq[W_ * 136];   // [w][cin], row stride 136 (272B, 16B-mult)

    bf16* orow = xqT + (size_t)blk * XP * CIN_;

    if (y == 0 || y == YP - 1) {
        f4 z = {0.f, 0.f, 0.f, 0.f};
        #pragma unroll
        for (int i = 0; i < 4; ++i) {
            int T = i * 256 + t;
            *(f4*)(orow + T * 8) = z;   // 8 bf16 zeros
        }
        return;
    }
    int h = y - 1;
    float act_s = p_act_s[0], act_q = p_act_q[0], azp = p_azp[0], ga = p_guard_a[0];
    float zp = azp * act_s / ga;
    float hi = zp + act_q - act_s;
    float inv_s = 1.0f / act_s;       // act_s = 2^-4 -> exact reciprocal

    // load + quantize into LDS (transposed: [w][cin])
    for (int i = 0; i < 28; ++i) {
        int e = i * 256 + t;          // < 7168
        int cin = e / 56;
        int w = e - cin * 56;
        float v = x[(((size_t)b * CIN_ + cin) * H_ + h) * W_ + w];
        v = fminf(fmaxf(v, zp), hi);
        float qv = ga * rintf((v - zp) * inv_s);   // even int in [0,510]: bf16-exact
        shq[w * 136 + cin] = (bf16)qv;
    }
    __syncthreads();
    // write out padded row, cin-contiguous 16B stores
    #pragma unroll
    for (int i = 0; i < 4; ++i) {
        int T = i * 256 + t;          // < 1024
        int xx = T >> 4;              // 0..63
        int c8 = (T & 15) * 8;
        bf16x8 v;
        if (xx >= 1 && xx <= W_) {
            v = *(const bf16x8*)(shq + (xx - 1) * 136 + c8);
        } else {
            #pragma unroll
            for (int j = 0; j < 8; ++j) v[j] = (bf16)0.0f;
        }
        *(bf16x8*)(orow + (size_t)xx * CIN_ + c8) = v;
    }
}

// ---------------------------------------------------------------------------
// Kernel W: pack weights (OIHW fp32) into per-tile linear bf16 images:
// flat = (((g*4 + cc)*2 + cb)*128 + m)*32 + kk ; cout=cb*128+m, cin=cc*32+kk,
// g = dy*3+dx. Each 4096-element tile is one GEMM A-tile (LDS image).
__global__ __launch_bounds__(256) void k_wpack(const float* __restrict__ w,
                                               bf16* __restrict__ wt)
{
    int o = blockIdx.x * 256 + threadIdx.x;   // < 294912
    int kk = o & 31;
    int m  = (o >> 5) & 127;
    int cb = (o >> 12) & 1;
    int cc = (o >> 13) & 3;
    int g  = o >> 15;
    int cout = cb * 128 + m;
    int cin  = cc * 32 + kk;
    int dy = g / 3, dx = g - dy * 3;
    float v = w[(((size_t)cout * CIN_ + cin) * 3 + dy) * 3 + dx];
    wt[o] = (bf16)v;
}

// ---------------------------------------------------------------------------
// Kernel S: s_pad[b][y][x] = sum_cin xqT (fp32, exact). One block per (b,y).
__global__ __launch_bounds__(256) void k_chsum(const bf16* __restrict__ xqT,
                                               float* __restrict__ s_pad)
{
    int blk = blockIdx.x;             // b*58 + y
    int t = threadIdx.x;
    int xx = t >> 2, pp = t & 3;
    const bf16* ptr = xqT + ((size_t)blk * XP + xx) * CIN_ + pp * 32;
    float sum = 0.f;
    #pragma unroll
    for (int j = 0; j < 4; ++j) {
        union { f4 v; unsigned short u[8]; } ld;
        ld.v = *(const f4*)(ptr + j * 8);
        #pragma unroll
        for (int k2 = 0; k2 < 8; ++k2)
            sum += __uint_as_float((unsigned)ld.u[k2] << 16);
    }
    __shared__ float part[256];
    part[t] = sum;
    __syncthreads();
    if (t < 64) {
        float s = part[t * 4] + part[t * 4 + 1] + part[t * 4 + 2] + part[t * 4 + 3];
        s_pad[(size_t)blk * XP + t] = s;
    }
}

// ---------------------------------------------------------------------------
// Kernel C2: 3x3 box sum of s_pad -> c2[b][h][w'] (w' in [0,64), garbage >=56)
__global__ __launch_bounds__(256) void k_box(const float* __restrict__ s_pad,
                                             float* __restrict__ c2)
{
    int o = blockIdx.x * 256 + threadIdx.x;   // < 57344
    int w = o & 63;
    int r = o >> 6;                   // b*56 + h
    int bb = r / 56, hh = r - bb * 56;
    const float* sp = s_pad + ((size_t)bb * YP + hh) * XP + w;
    float acc = 0.f;
    #pragma unroll
    for (int dy = 0; dy < 3; ++dy)
        #pragma unroll
        for (int dx = 0; dx < 3; ++dx)
            acc += sp[dy * XP + dx];
    c2[o] = acc;
}

// ---------------------------------------------------------------------------
// GEMM: C[cout][n] over K=(g=dy*3+dx, cin). Macro tile 128(cout) x 128(n);
// n-tile = 2 output rows x 64 (w padded; w>=56 discarded). 4 waves, each 64x64
// via 4x4 MFMA 16x16x32 frags. Activation halo [4y][64x][32cin] staged once
// per cin-chunk, reused by all 9 taps via LDS offsets.
__global__ __launch_bounds__(256) void k_gemm(
    const bf16*  __restrict__ xqT,   // [B][58][64][128]
    const bf16*  __restrict__ wt,    // packed tiles
    const float* __restrict__ c2,    // [B][56][64]
    const float* __restrict__ wzp,   // [256]
    const float* __restrict__ fps,   // [256]
    const float* __restrict__ bias,  // [256][56][56]
    const float* __restrict__ p_gw,  // guard_w
    float* __restrict__ out)         // [B][256][56][56]
{
    __shared__ __align__(16) bf16 Bh[5 * XP * 32];   // 20 KB ([yy][x][kk] + guard)
    __shared__ __align__(16) bf16 As[128 * 32];      // 8 KB  ([m][kk])

    int tid = threadIdx.x;
    int wv = tid >> 6, lane = tid & 63;
    int xl = lane & 15, q = lane >> 4;
    int p = blockIdx.x, cb = blockIdx.y;
    int b = p / 28, hp = p - b * 28;
    int h = hp * 2;
    int wm0 = (wv >> 1) * 64, wn0 = (wv & 1) * 64;

    // zero Bh guard region (read only by discarded w>=56 outputs, but keep
    // it NaN-free)
    {
        bf16x8 z;
        #pragma unroll
        for (int j = 0; j < 8; ++j) z[j] = (bf16)0.0f;
        *(bf16x8*)(Bh + 8192 + tid * 8) = z;
    }

    f32x4 acc[4][4];
    #pragma unroll
    for (int mi = 0; mi < 4; ++mi)
        #pragma unroll
        for (int ni = 0; ni < 4; ++ni)
            acc[mi][ni] = (f32x4){0.f, 0.f, 0.f, 0.f};

    const bf16* xb = xqT + (size_t)(b * YP + h) * XP * CIN_;

    int a_off[4];
    #pragma unroll
    for (int mi = 0; mi < 4; ++mi)
        a_off[mi] = (wm0 + mi * 16 + xl) * 32 + q * 8;
    int row = wn0 >> 6;                // 0 or 1, wave-uniform
    int bn_off[4];
    #pragma unroll
    for (int ni = 0; ni < 4; ++ni) {
        int n = wn0 + ni * 16 + xl;
        int wp = n & 63;
        bn_off[ni] = (row * XP + wp) * 32 + q * 8;
    }

    for (int cc = 0; cc < 4; ++cc) {
        for (int g = 0; g < 9; ++g) {
            __syncthreads();           // prior readers done before overwrite
            if (g == 0) {
                // stage activation halo: 4 y-rows x 64 x x 32 cin = 16 KB
                #pragma unroll
                for (int i = 0; i < 4; ++i) {
                    int T = i * 256 + tid;
                    int kk8 = (T & 3) * 8;
                    int xx = (T >> 2) & 63;
                    int yy = T >> 8;
                    const bf16* src = xb + (size_t)(yy * XP + xx) * CIN_ + cc * 32 + kk8;
                    bf16* dst = Bh + (i * 256 + wv * 64) * 8;   // wave-uniform
                    gload16(src, dst);
                }
            }
            {
                int tile = (g * 4 + cc) * 2 + cb;
                const bf16* wsrc = wt + (size_t)tile * 4096;
                #pragma unroll
                for (int i = 0; i < 2; ++i) {
                    const bf16* src = wsrc + (i * 256 + tid) * 8;
                    bf16* dst = As + (i * 256 + wv * 64) * 8;   // wave-uniform
                    gload16(src, dst);
                }
            }
            __syncthreads();           // staging visible (vmcnt drained)

            int dy = g / 3, dx = g - dy * 3;
            int boff = (dy * XP + dx) * 32;
            bf16x8 af[4], bfr[4];
            #pragma unroll
            for (int mi = 0; mi < 4; ++mi)
                af[mi] = *(const bf16x8*)(As + a_off[mi]);
            #pragma unroll
            for (int ni = 0; ni < 4; ++ni)
                bfr[ni] = *(const bf16x8*)(Bh + bn_off[ni] + boff);
            #pragma unroll
            for (int mi = 0; mi < 4; ++mi)
                #pragma unroll
                for (int ni = 0; ni < 4; ++ni)
                    acc[mi][ni] = __builtin_amdgcn_mfma_f32_16x16x32_bf16(
                        af[mi], bfr[ni], acc[mi][ni], 0, 0, 0);
        }
    }

    // Epilogue: out = (guard_w*c1 + wzp[cout]*c2) * fp_scale[cout] + bias
    int hrow = h + row;
    float gw = p_gw[0];
    float c2v[4]; int wp4[4];
    #pragma unroll
    for (int ni = 0; ni < 4; ++ni) {
        int n = wn0 + ni * 16 + xl;
        int wp = n & 63;
        wp4[ni] = wp;
        c2v[ni] = (wp < W_) ? c2[((size_t)b * H_ + hrow) * XP + wp] : 0.0f;
    }
    #pragma unroll
    for (int mi = 0; mi < 4; ++mi) {
        #pragma unroll
        for (int r = 0; r < 4; ++r) {
            int cout = cb * 128 + wm0 + mi * 16 + q * 4 + r;
            float wz = wzp[cout], fs = fps[cout];
            const float* brow = bias + ((size_t)cout * H_ + hrow) * W_;
            float* orow = out + (((size_t)b * COUT_ + cout) * H_ + hrow) * W_;
            #pragma unroll
            for (int ni = 0; ni < 4; ++ni) {
                int wp = wp4[ni];
                if (wp < W_) {
                    float v = gw * acc[mi][ni][r] + wz * c2v[ni];
                    orow[wp] = v * fs + brow[wp];
                }
            }
        }
    }
}

// ---------------------------------------------------------------------------
extern "C" void kernel_launch(void* const* d_in, const int* in_sizes, int n_in,
                              void* d_out, int out_size, void* d_ws, size_t ws_size,
                              hipStream_t stream)
{
    const float* x     = (const float*)d_in[0];
    const float* wht   = (const float*)d_in[1];
    const float* act_s = (const float*)d_in[2];
    const float* act_q = (const float*)d_in[3];
    const float* azp   = (const float*)d_in[4];
    const float* wzp   = (const float*)d_in[5];
    const float* fps   = (const float*)d_in[6];
    const float* bias  = (const float*)d_in[7];
    const float* ga    = (const float*)d_in[8];
    const float* gw    = (const float*)d_in[9];
    float* out = (float*)d_out;

    char* ws = (char*)d_ws;
    // workspace layout (16B aligned):
    //   xqT   : 16*58*64*128 bf16 = 15,204,352 B
    //   wt    : 294912 bf16       =    589,824 B
    //   s_pad : (59392+64) fp32   =    237,824 B
    //   c2    : 57344 fp32        =    229,376 B   (total ~16.3 MB)
    bf16*  xqT   = (bf16*)(ws);
    bf16*  wt    = (bf16*)(ws + 15204352);
    float* s_pad = (float*)(ws + 15204352 + 589824);
    float* c2    = (float*)(ws + 15204352 + 589824 + 237824);

    k_quant<<<dim3(16 * YP), dim3(256), 0, stream>>>(x, act_s, act_q, azp, ga, xqT);
    k_wpack<<<dim3(1152),    dim3(256), 0, stream>>>(wht, wt);
    k_chsum<<<dim3(16 * YP), dim3(256), 0, stream>>>(xqT, s_pad);
    k_box  <<<dim3(224),     dim3(256), 0, stream>>>(s_pad, c2);
    k_gemm <<<dim3(448, 2),  dim3(256), 0, stream>>>(xqT, wt, c2, wzp, fps, bias, gw, out);
}

// Round 2
// 172.963 us; speedup vs baseline: 1.0185x; 1.0185x over previous
//
#include <hip/hip_runtime.h>

#define B_    16
#define CIN_  128
#define COUT_ 256
#define H_    56
#define W_    56
#define YP    58
#define XP    64

typedef __bf16 bf16;
typedef bf16  bf16x8 __attribute__((ext_vector_type(8)));
typedef float f32x4  __attribute__((ext_vector_type(4)));
typedef float f4     __attribute__((ext_vector_type(4)));

// Bh buffer: 4 rows x 64 cols x 32 k = 8192 el + 64 el guard (reads of
// discarded cols wp+dx>=64 land in els [8192,8256)).
#define BH_ELS 8256

// ---------------------------------------------------------------------------
// async global->LDS, 16B per lane. LDS dest is wave-uniform base; HW writes
// lane l at base + l*16B.
__device__ __forceinline__ void gload16(const bf16* g, bf16* l) {
    __builtin_amdgcn_global_load_lds(
        (const __attribute__((address_space(1))) unsigned int*)g,
        (__attribute__((address_space(3))) unsigned int*)l,
        16, 0, 0);
}

// ---------------------------------------------------------------------------
// Kernel A: quantize x (NCHW fp32) -> xqT[b][y][x][cin] bf16 (padded), and
// fused channel-sum -> s_pad[b][y][x] fp32. One block per (b, y) row.
__global__ __launch_bounds__(256) void k_quant(
    const float* __restrict__ x,
    const float* __restrict__ p_act_s, const float* __restrict__ p_act_q,
    const float* __restrict__ p_azp,  const float* __restrict__ p_guard_a,
    bf16* __restrict__ xqT, float* __restrict__ s_pad)
{
    int blk = blockIdx.x;            // b*58 + y
    int b = blk / YP, y = blk - b * YP;
    int t = threadIdx.x;
    __shared__ bf16 shq[W_ * 136];   // [w][cin], row stride 136 el

    bf16* orow = xqT + (size_t)blk * XP * CIN_;

    if (y == 0 || y == YP - 1) {
        f4 z = {0.f, 0.f, 0.f, 0.f};
        #pragma unroll
        for (int i = 0; i < 4; ++i) {
            int T = i * 256 + t;
            *(f4*)(orow + T * 8) = z;   // 8 bf16 zeros
        }
        if (t < XP) s_pad[(size_t)blk * XP + t] = 0.0f;
        return;
    }
    int h = y - 1;
    float act_s = p_act_s[0], act_q = p_act_q[0], azp = p_azp[0], ga = p_guard_a[0];
    float zp = azp * act_s / ga;
    float hi = zp + act_q - act_s;
    float inv_s = 1.0f / act_s;       // act_s = 2^-4 -> exact reciprocal

    for (int i = 0; i < 28; ++i) {
        int e = i * 256 + t;          // < 7168
        int cin = e / 56;
        int w = e - cin * 56;
        float v = x[(((size_t)b * CIN_ + cin) * H_ + h) * W_ + w];
        v = fminf(fmaxf(v, zp), hi);
        float qv = ga * rintf((v - zp) * inv_s);   // even int in [0,510]: bf16-exact
        shq[w * 136 + cin] = (bf16)qv;
    }
    __syncthreads();
    // write padded row (cin-contiguous 16B stores) + fused channel-sum
    #pragma unroll
    for (int i = 0; i < 4; ++i) {
        int T = i * 256 + t;          // < 1024
        int xx = T >> 4;              // 0..63
        int c8 = (T & 15) * 8;
        bf16x8 v;
        if (xx >= 1 && xx <= W_) {
            v = *(const bf16x8*)(shq + (xx - 1) * 136 + c8);
        } else {
            #pragma unroll
            for (int j = 0; j < 8; ++j) v[j] = (bf16)0.0f;
        }
        *(bf16x8*)(orow + (size_t)xx * CIN_ + c8) = v;
        float sum = 0.f;
        #pragma unroll
        for (int j = 0; j < 8; ++j) sum += (float)v[j];
        sum += __shfl_xor(sum, 1);
        sum += __shfl_xor(sum, 2);
        sum += __shfl_xor(sum, 4);
        sum += __shfl_xor(sum, 8);
        if ((t & 15) == 0) s_pad[(size_t)blk * XP + xx] = sum;
    }
}

// ---------------------------------------------------------------------------
// Kernel W: pack weights (OIHW fp32) into swizzled LDS-tile images. Physical
// index o: j=o&7, slot p=(o>>3)&3, m=(o>>5)&127, cb, cc, g. Logical k-slot
// q = p ^ ((m>>1)&3)  (bank-conflict swizzle, undone at read time).
__global__ __launch_bounds__(256) void k_wpack(const float* __restrict__ w,
                                               bf16* __restrict__ wt)
{
    int o = blockIdx.x * 256 + threadIdx.x;   // < 294912
    int j  = o & 7;
    int p  = (o >> 3) & 3;
    int m  = (o >> 5) & 127;
    int cb = (o >> 12) & 1;
    int cc = (o >> 13) & 3;
    int g  = o >> 15;
    int q  = p ^ ((m >> 1) & 3);
    int cout = cb * 128 + m;
    int cin  = cc * 32 + q * 8 + j;
    int dy = g / 3, dx = g - dy * 3;
    float v = w[(((size_t)cout * CIN_ + cin) * 3 + dy) * 3 + dx];
    wt[o] = (bf16)v;
}

// ---------------------------------------------------------------------------
// Kernel C2: 3x3 box sum of s_pad -> c2[b][h][w'] (w' in [0,64))
__global__ __launch_bounds__(256) void k_box(const float* __restrict__ s_pad,
                                             float* __restrict__ c2)
{
    int o = blockIdx.x * 256 + threadIdx.x;   // < 57344
    int w = o & 63;
    int r = o >> 6;                   // b*56 + h
    int bb = r / 56, hh = r - bb * 56;
    const float* sp = s_pad + ((size_t)bb * YP + hh) * XP + w;
    float acc = 0.f;
    #pragma unroll
    for (int dy = 0; dy < 3; ++dy)
        #pragma unroll
        for (int dx = 0; dx < 3; ++dx)
            acc += sp[dy * XP + dx];
    c2[o] = acc;
}

// ---------------------------------------------------------------------------
// GEMM: 128(cout) x 128(n=2 rows x 64w) tile, K = (cc 0..3) x (g 0..8) x 32cin.
// Single-barrier double-buffered pipeline: prefetch (i+1) staged before
// compute(i); one __syncthreads per K-iteration (36 total). LDS fragment
// addresses swizzled (slot ^= (row>>1)&3) -> 2-way max bank aliasing (free).
__global__ __launch_bounds__(256, 3) void k_gemm(
    const bf16*  __restrict__ xqT,   // [B][58][64][128]
    const bf16*  __restrict__ wt,    // packed+swizzled tiles
    const float* __restrict__ c2,    // [B][56][64]
    const float* __restrict__ wzp,   // [256]
    const float* __restrict__ fps,   // [256]
    const float* __restrict__ bias,  // [256][56][56]
    const float* __restrict__ p_gw,  // guard_w
    float* __restrict__ out)         // [B][256][56][56]
{
    __shared__ __align__(16) bf16 Bh[2 * BH_ELS];   // 2 x 16.5 KB
    __shared__ __align__(16) bf16 As[2 * 4096];     // 2 x 8 KB

    int tid = threadIdx.x;
    int wv = tid >> 6, lane = tid & 63;
    int xl = lane & 15, q = lane >> 4;
    int p = blockIdx.x, cb = blockIdx.y;
    int b = p / 28, hp = p - b * 28;
    int h = hp * 2;
    int wm0 = (wv >> 1) * 64, wn0 = (wv & 1) * 64;
    int row = wn0 >> 6;                // 0 or 1, wave-uniform

    // zero the 64-el guard of each Bh buffer (wrap-reads of discarded cols)
    if (tid < 16) {
        bf16x8 z;
        #pragma unroll
        for (int j = 0; j < 8; ++j) z[j] = (bf16)0.0f;
        *(bf16x8*)(Bh + (tid >> 3) * BH_ELS + 8192 + (tid & 7) * 8) = z;
    }

    f32x4 acc[4][4];
    #pragma unroll
    for (int mi = 0; mi < 4; ++mi)
        #pragma unroll
        for (int ni = 0; ni < 4; ++ni)
            acc[mi][ni] = (f32x4){0.f, 0.f, 0.f, 0.f};

    const bf16* xb = xqT + (size_t)(b * YP + h) * XP * CIN_;

    // fragment base offsets (swizzled slot): A row m = wm0+mi*16+xl
    int a_base = (wm0 + xl) * 32 + (q ^ ((xl >> 1) & 3)) * 8;

    // ---- staging helpers (inline) ----
    // stage As[buf] <- weight tile (g,cc): linear copy, 2 rounds
    #define STAGE_A(buf_, g_, cc_)                                          \
        {                                                                   \
            const bf16* wsrc = wt + (size_t)(((g_)*4 + (cc_))*2 + cb) * 4096; \
            bf16* dstb = As + (buf_) * 4096;                                \
            _Pragma("unroll")                                               \
            for (int r_ = 0; r_ < 2; ++r_)                                  \
                gload16(wsrc + (r_ * 256 + tid) * 8,                        \
                        dstb + (r_ * 256 + wv * 64) * 8);                   \
        }
    // stage Bh[buf] <- activation halo for cin-chunk cc_: 4 rounds, lane
    // permuted so the LDS image is slot-swizzled.
    #define STAGE_B(buf_, cc_)                                              \
        {                                                                   \
            bf16* dstb = Bh + (buf_) * BH_ELS;                              \
            _Pragma("unroll")                                               \
            for (int r_ = 0; r_ < 4; ++r_) {                                \
                int T_ = r_ * 256 + tid;                                    \
                int p_ = T_ & 3;                                            \
                int x_ = (T_ >> 2) & 63;                                    \
                int yy_ = T_ >> 8;                                          \
                int q_ = p_ ^ ((x_ >> 1) & 3);                              \
                gload16(xb + (size_t)(yy_ * XP + x_) * CIN_ + (cc_) * 32 + q_ * 8, \
                        dstb + (r_ * 256 + wv * 64) * 8);                   \
            }                                                               \
        }

    // prologue: stage iteration 0
    STAGE_A(0, 0, 0)
    STAGE_B(0, 0)
    __syncthreads();   // drains vmcnt: buffers 0 ready

    int cc = 0, g = 0;
    for (int i = 0; i < 36; ++i) {
        // issue prefetch for iteration i+1 into the other buffers
        if (i < 35) {
            int gn = g + 1, ccn = cc;
            if (gn == 9) { gn = 0; ccn = cc + 1; }
            STAGE_A((i + 1) & 1, gn, ccn)
            if (gn == 0) STAGE_B(ccn & 1, ccn)
        }
        // compute iteration i
        {
            const bf16* Ab = As + (i & 1) * 4096;
            const bf16* Bb = Bh + (cc & 1) * BH_ELS;
            int dy = g / 3, dx = g - dy * 3;
            int slot_b = q ^ (((xl + dx) >> 1) & 3);
            int bn_base = ((row + dy) * XP + xl + dx) * 32 + slot_b * 8;
            bf16x8 af[4], bfr[4];
            #pragma unroll
            for (int mi = 0; mi < 4; ++mi)
                af[mi] = *(const bf16x8*)(Ab + a_base + mi * 512);
            #pragma unroll
            for (int ni = 0; ni < 4; ++ni)
                bfr[ni] = *(const bf16x8*)(Bb + bn_base + ni * 512);
            #pragma unroll
            for (int mi = 0; mi < 4; ++mi)
                #pragma unroll
                for (int ni = 0; ni < 4; ++ni)
                    acc[mi][ni] = __builtin_amdgcn_mfma_f32_16x16x32_bf16(
                        af[mi], bfr[ni], acc[mi][ni], 0, 0, 0);
        }
        __syncthreads();   // readers done + prefetch vmcnt drained
        if (++g == 9) { g = 0; ++cc; }
    }

    // Epilogue: out = (guard_w*c1 + wzp[cout]*c2) * fp_scale[cout] + bias
    int hrow = h + row;
    float gw = p_gw[0];
    float c2v[4]; int wp4[4];
    #pragma unroll
    for (int ni = 0; ni < 4; ++ni) {
        int wp = ni * 16 + xl;
        wp4[ni] = wp;
        c2v[ni] = (wp < W_) ? c2[((size_t)b * H_ + hrow) * XP + wp] : 0.0f;
    }
    #pragma unroll
    for (int mi = 0; mi < 4; ++mi) {
        #pragma unroll
        for (int r = 0; r < 4; ++r) {
            int cout = cb * 128 + wm0 + mi * 16 + q * 4 + r;
            float wz = wzp[cout], fs = fps[cout];
            const float* brow = bias + ((size_t)cout * H_ + hrow) * W_;
            float* orow = out + (((size_t)b * COUT_ + cout) * H_ + hrow) * W_;
            #pragma unroll
            for (int ni = 0; ni < 4; ++ni) {
                int wp = wp4[ni];
                if (wp < W_) {
                    float v = gw * acc[mi][ni][r] + wz * c2v[ni];
                    orow[wp] = v * fs + brow[wp];
                }
            }
        }
    }
}

// ---------------------------------------------------------------------------
extern "C" void kernel_launch(void* const* d_in, const int* in_sizes, int n_in,
                              void* d_out, int out_size, void* d_ws, size_t ws_size,
                              hipStream_t stream)
{
    const float* x     = (const float*)d_in[0];
    const float* wht   = (const float*)d_in[1];
    const float* act_s = (const float*)d_in[2];
    const float* act_q = (const float*)d_in[3];
    const float* azp   = (const float*)d_in[4];
    const float* wzp   = (const float*)d_in[5];
    const float* fps   = (const float*)d_in[6];
    const float* bias  = (const float*)d_in[7];
    const float* ga    = (const float*)d_in[8];
    const float* gw    = (const float*)d_in[9];
    float* out = (float*)d_out;

    char* ws = (char*)d_ws;
    // workspace layout (16B aligned):
    //   xqT   : 16*58*64*128 bf16 = 15,204,352 B
    //   wt    : 294912 bf16       =    589,824 B
    //   s_pad : 59456 fp32        =    237,824 B
    //   c2    : 57344 fp32        =    229,376 B
    bf16*  xqT   = (bf16*)(ws);
    bf16*  wt    = (bf16*)(ws + 15204352);
    float* s_pad = (float*)(ws + 15204352 + 589824);
    float* c2    = (float*)(ws + 15204352 + 589824 + 237824);

    k_quant<<<dim3(16 * YP), dim3(256), 0, stream>>>(x, act_s, act_q, azp, ga, xqT, s_pad);
    k_wpack<<<dim3(1152),    dim3(256), 0, stream>>>(wht, wt);
    k_box  <<<dim3(224),     dim3(256), 0, stream>>>(s_pad, c2);
    k_gemm <<<dim3(448, 2),  dim3(256), 0, stream>>>(xqT, wt, c2, wzp, fps, bias, gw, out);
}

// Round 3
// 143.853 us; speedup vs baseline: 1.2246x; 1.2024x over previous
//
#include <hip/hip_runtime.h>

#define B_    16
#define CIN_  128
#define COUT_ 256
#define H_    56
#define W_    56
#define YP    58
#define XP    64

typedef int   i32x4 __attribute__((ext_vector_type(4)));
typedef float f4    __attribute__((ext_vector_type(4)));

#define AS_SZ 8192     // 128 cout x 64 k  (i8)
#define BH_SZ 24704    // 6 rows x 64 x x 64 k (24576) + 128 B guard

// async global->LDS, 16B per lane; LDS dest wave-uniform base, lane l lands
// at base + l*16.
__device__ __forceinline__ void gload16(const void* g, void* l) {
    __builtin_amdgcn_global_load_lds(
        (const __attribute__((address_space(1))) unsigned int*)g,
        (__attribute__((address_space(3))) unsigned int*)l,
        16, 0, 0);
}

// ---------------------------------------------------------------------------
// Fused prep kernel, block-range partitioned:
//   [0,928)      : quantize x -> xqU i8 (u = xq/2-128, pad = -128) + s_pad
//   [928,1216)   : pack weights -> i8 tiles [tile(36)][m(128)][k(64)]
//   [1216,1232)  : Wsum[cout] = sum over cin,ky,kx of weight
__global__ __launch_bounds__(256) void k_prep(
    const float* __restrict__ x, const float* __restrict__ w,
    const float* __restrict__ p_act_s, const float* __restrict__ p_act_q,
    const float* __restrict__ p_azp,  const float* __restrict__ p_guard_a,
    signed char* __restrict__ xqU, signed char* __restrict__ wt,
    float* __restrict__ s_pad, float* __restrict__ Wsum)
{
    int t = threadIdx.x;
    int blk = blockIdx.x;

    if (blk < 928) {
        // ---- quantize one (b, padded-y) row ----
        int b = blk / YP, y = blk - b * YP;
        __shared__ signed char shq[W_ * 144];   // [w][cin], stride 144 (16-mult)
        signed char* orow = xqU + (size_t)blk * XP * CIN_;

        if (y == 0 || y == YP - 1) {
            i32x4 pv = {(int)0x80808080, (int)0x80808080,
                        (int)0x80808080, (int)0x80808080};
            *(i32x4*)(orow + t * 32)      = pv;
            *(i32x4*)(orow + t * 32 + 16) = pv;
            if (t < XP) s_pad[(size_t)blk * XP + t] = 0.0f;
            return;
        }
        int h = y - 1;
        float act_s = p_act_s[0], act_q = p_act_q[0];
        float azp = p_azp[0], ga = p_guard_a[0];
        float zp = azp * act_s / ga;
        float hi = zp + act_q - act_s;
        float inv_s = 1.0f / act_s;            // act_s = 2^-4: exact

        for (int i = 0; i < 28; ++i) {
            int e = i * 256 + t;               // < 7168
            int cin = e / 56;
            int ww = e - cin * 56;
            float v = x[(((size_t)b * CIN_ + cin) * H_ + h) * W_ + ww];
            v = fminf(fmaxf(v, zp), hi);
            float r = rintf((v - zp) * inv_s);        // [0,255] integer
            float uq = rintf(ga * r * 0.5f) - 128.0f; // = r-128 (ga==2)
            shq[ww * 144 + cin] = (signed char)(int)uq;
        }
        __syncthreads();
        // write padded row (16B stores, cin contiguous) + channel-sum
        #pragma unroll
        for (int i = 0; i < 2; ++i) {
            int T = i * 256 + t;               // < 512
            int xx = T >> 3;                   // 0..63
            int c16 = T & 7;
            union { i32x4 v; signed char c[16]; } u;
            if (xx >= 1 && xx <= W_) {
                u.v = *(const i32x4*)(shq + (xx - 1) * 144 + c16 * 16);
            } else {
                u.v = (i32x4){(int)0x80808080, (int)0x80808080,
                              (int)0x80808080, (int)0x80808080};
            }
            *(i32x4*)(orow + (size_t)xx * CIN_ + c16 * 16) = u.v;
            int sum = 0;
            #pragma unroll
            for (int j = 0; j < 16; ++j) sum += (int)u.c[j];
            sum += __shfl_xor(sum, 1);
            sum += __shfl_xor(sum, 2);
            sum += __shfl_xor(sum, 4);
            // sum(xq) = 2*sum(u) + 256*128; pads give exactly 0
            if (c16 == 0)
                s_pad[(size_t)blk * XP + xx] = (float)(2 * sum + 32768);
        }
        return;
    }

    if (blk < 1216) {
        // ---- weight pack: 4 consecutive k per thread ----
        int o = ((blk - 928) * 256 + t) * 4;   // < 294912
        int tile = o >> 13;                    // (g*2+cc)*2+cb
        int m    = (o >> 6) & 127;
        int kk   = o & 63;                     // multiple of 4
        int cb = tile & 1, cc = (tile >> 1) & 1, g = tile >> 2;
        int cout = cb * 128 + m;
        int cin0 = cc * 64 + kk;
        int dy = g / 3, dx = g - dy * 3;
        union { int v; signed char c[4]; } pk;
        #pragma unroll
        for (int j = 0; j < 4; ++j) {
            float v = w[(size_t)cout * 1152 + (cin0 + j) * 9 + dy * 3 + dx];
            pk.c[j] = (signed char)(int)v;
        }
        *(int*)(wt + o) = pk.v;
        return;
    }

    {
        // ---- Wsum: 16 couts per block, 16 lanes per cout ----
        int bw = blk - 1216;
        int cout = bw * 16 + (t >> 4);
        int part = t & 15;
        const float* base = w + (size_t)cout * 1152 + part * 72;
        float s = 0.f;
        for (int j = 0; j < 72; ++j) s += base[j];
        s += __shfl_xor(s, 1);
        s += __shfl_xor(s, 2);
        s += __shfl_xor(s, 4);
        s += __shfl_xor(s, 8);
        if (part == 0) Wsum[cout] = s;
        return;
    }
}

// ---------------------------------------------------------------------------
// i8 implicit-GEMM: block tile 128(cout, via cb) x 256(n = 4 rows x 64 w).
// K = (cc 0..1)x(g 0..8)x(64 cin), 18 iterations, mfma_i32_16x16x64_i8.
// Wave tile 64x128 (4 mi x 8 ni frags). Double-buffered single-barrier loop.
// c1 = 2*acc + 256*Wsum[cout]; c2 box-filter precomputed per block from s_pad.
__global__ __launch_bounds__(256, 2) void k_gemm(
    const signed char* __restrict__ xqU,  // [B][58][64][128] i8
    const signed char* __restrict__ wt,   // 36 tiles x [128][64] i8
    const float* __restrict__ s_pad,      // [B*58][64]
    const float* __restrict__ Wsum,       // [256]
    const float* __restrict__ wzp,        // [256]
    const float* __restrict__ fps,        // [256]
    const float* __restrict__ bias,       // [256][56][56]
    const float* __restrict__ p_gw,       // guard_w
    float* __restrict__ out)              // [B][256][56][56]
{
    __shared__ __align__(16) signed char As[2][AS_SZ];
    __shared__ __align__(16) signed char Bh[2][BH_SZ];
    __shared__ float c2s[4 * 56];

    int tid = threadIdx.x;
    int wv = tid >> 6, lane = tid & 63;
    int xl = lane & 15, q = lane >> 4;
    int p = blockIdx.x, cb = blockIdx.y;
    int b = p / 14, hp = p - b * 14;
    int h = hp * 4;                        // 4 output rows per block
    int wm0 = (wv >> 1) * 64, wn0 = (wv & 1) * 128;

    // c2 box filter for this block's 4 output rows (s_pad is L2-hot)
    if (tid < 224) {
        int rr = tid / 56, wp = tid - rr * 56;
        const float* sp = s_pad + ((size_t)(b * YP + h + rr)) * XP + wp;
        float a = 0.f;
        #pragma unroll
        for (int dy = 0; dy < 3; ++dy)
            #pragma unroll
            for (int dx = 0; dx < 3; ++dx)
                a += sp[dy * XP + dx];
        c2s[tid] = a;
    }

    i32x4 acc[4][8];
    #pragma unroll
    for (int mi = 0; mi < 4; ++mi)
        #pragma unroll
        for (int ni = 0; ni < 8; ++ni)
            acc[mi][ni] = (i32x4){0, 0, 0, 0};

    const signed char* xb = xqU + (size_t)(b * YP + h) * XP * CIN_;

    int a_base = (wm0 + xl) * 64 + q * 16;    // bytes into As tile
    int bn_base[8];
    #pragma unroll
    for (int ni = 0; ni < 8; ++ni) {
        int n = wn0 + ni * 16 + xl;
        int rn = n >> 6, wp = n & 63;
        bn_base[ni] = (rn * XP + wp) * 64 + q * 16;
    }

    #define STAGE_A(buf_, g_, cc_)                                          \
        {                                                                   \
            const signed char* wsrc = wt + (size_t)((((g_)*2+(cc_))*2)+cb) * 8192; \
            signed char* dstb = As[buf_];                                   \
            _Pragma("unroll")                                               \
            for (int r_ = 0; r_ < 2; ++r_)                                  \
                gload16(wsrc + (r_ * 256 + tid) * 16,                       \
                        dstb + (r_ * 256 + wv * 64) * 16);                  \
        }
    #define STAGE_B(buf_, cc_)                                              \
        {                                                                   \
            signed char* dstb = Bh[buf_];                                   \
            _Pragma("unroll")                                               \
            for (int r_ = 0; r_ < 6; ++r_) {                                \
                int T_ = r_ * 256 + tid;                                    \
                int p_ = T_ & 3;                                            \
                int x_ = (T_ >> 2) & 63;                                    \
                int yy_ = T_ >> 8;                                          \
                gload16(xb + (size_t)(yy_ * XP + x_) * CIN_ + (cc_) * 64 + p_ * 16, \
                        dstb + (r_ * 256 + wv * 64) * 16);                  \
            }                                                               \
        }

    STAGE_A(0, 0, 0)
    STAGE_B(0, 0)
    __syncthreads();   // buffers 0 ready (vmcnt drained); c2s also visible

    for (int i = 0; i < 18; ++i) {
        int cc = (i >= 9) ? 1 : 0;
        int g = i - cc * 9;
        if (i < 17) {
            int gn = g + 1, ccn = cc;
            if (gn == 9) { gn = 0; ccn = 1; }
            STAGE_A((i + 1) & 1, gn, ccn)
            if (gn == 0) STAGE_B(1, 1)
        }
        {
            const signed char* Ab = As[i & 1];
            const signed char* Bb = Bh[cc];
            int dy = g / 3, dx = g - dy * 3;
            int boff = dy * (XP * 64) + dx * 64;
            i32x4 af[4], bfr[8];
            #pragma unroll
            for (int mi = 0; mi < 4; ++mi)
                af[mi] = *(const i32x4*)(Ab + a_base + mi * 1024);
            #pragma unroll
            for (int ni = 0; ni < 8; ++ni)
                bfr[ni] = *(const i32x4*)(Bb + bn_base[ni] + boff);
            #pragma unroll
            for (int mi = 0; mi < 4; ++mi)
                #pragma unroll
                for (int ni = 0; ni < 8; ++ni)
                    acc[mi][ni] = __builtin_amdgcn_mfma_i32_16x16x64_i8(
                        af[mi], bfr[ni], acc[mi][ni], 0, 0, 0);
        }
        __syncthreads();
    }

    // Epilogue: c1 = 2*acc + 256*Wsum; out = (gw*c1 + wzp*c2)*fps + bias
    float gw = p_gw[0];
    #pragma unroll
    for (int mi = 0; mi < 4; ++mi) {
        #pragma unroll
        for (int r = 0; r < 4; ++r) {
            int cout = cb * 128 + wm0 + mi * 16 + q * 4 + r;
            float wz = wzp[cout], fs = fps[cout], ws = Wsum[cout];
            #pragma unroll
            for (int ni = 0; ni < 8; ++ni) {
                int n = wn0 + ni * 16 + xl;
                int wp = n & 63;
                if (wp < W_) {
                    int rn = n >> 6;
                    int hrow = h + rn;
                    float c1 = 2.0f * (float)acc[mi][ni][r] + 256.0f * ws;
                    float v = gw * c1 + wz * c2s[rn * 56 + wp];
                    out[(((size_t)b * COUT_ + cout) * H_ + hrow) * W_ + wp] =
                        v * fs + bias[((size_t)cout * H_ + hrow) * W_ + wp];
                }
            }
        }
    }
}

// ---------------------------------------------------------------------------
extern "C" void kernel_launch(void* const* d_in, const int* in_sizes, int n_in,
                              void* d_out, int out_size, void* d_ws, size_t ws_size,
                              hipStream_t stream)
{
    const float* x     = (const float*)d_in[0];
    const float* wht   = (const float*)d_in[1];
    const float* act_s = (const float*)d_in[2];
    const float* act_q = (const float*)d_in[3];
    const float* azp   = (const float*)d_in[4];
    const float* wzp   = (const float*)d_in[5];
    const float* fps   = (const float*)d_in[6];
    const float* bias  = (const float*)d_in[7];
    const float* ga    = (const float*)d_in[8];
    const float* gw    = (const float*)d_in[9];
    float* out = (float*)d_out;

    char* ws = (char*)d_ws;
    // workspace (16B-aligned offsets):
    //   xqU  : 16*58*64*128 i8 = 7,602,176 B
    //   wt   : 294,912 B
    //   s_pad: 59,392 fp32     =   237,568 B
    //   Wsum : 256 fp32        =     1,024 B      (total ~8.1 MB)
    signed char* xqU  = (signed char*)(ws);
    signed char* wt   = (signed char*)(ws + 7602176);
    float*       spad = (float*)(ws + 7602176 + 294912);
    float*       Wsum = (float*)(ws + 7602176 + 294912 + 237568);

    k_prep<<<dim3(1232), dim3(256), 0, stream>>>(
        x, wht, act_s, act_q, azp, ga, xqU, wt, spad, Wsum);
    k_gemm<<<dim3(224, 2), dim3(256), 0, stream>>>(
        xqU, wt, spad, Wsum, wzp, fps, bias, gw, out);
}